// Round 5
// baseline (280.380 us; speedup 1.0000x reference)
//
#include <hip/hip_runtime.h>
#include <hip/hip_bf16.h>
#include <stdint.h>

#define EMBED 1024
#define HEADS 16
#define CTX   2048
#define BATCH 4
#define HD    64
#define M_TOT (BATCH*CTX)   // 8192

typedef unsigned short u16;
typedef __attribute__((ext_vector_type(8))) short short8;   // 8 bf16 (4 VGPRs)
typedef __attribute__((ext_vector_type(4))) float floatx4;  // MFMA C/D

typedef const __attribute__((address_space(1))) unsigned int g_u32;
typedef __attribute__((address_space(3))) unsigned int l_u32;

__device__ __forceinline__ void async16(const void* g, void* l) {
    __builtin_amdgcn_global_load_lds((g_u32*)g, (l_u32*)l, 16, 0, 0);
}

__device__ __forceinline__ u16 f2bf(float f) {          // round-nearest-even
    uint32_t u = __float_as_uint(f);
    uint32_t r = (u + 0x7FFFu + ((u >> 16) & 1u)) >> 16;
    return (u16)r;
}
__device__ __forceinline__ u16 f2bf_rtz(float f) {      // truncate (for P in [0,1])
    return (u16)(__float_as_uint(f) >> 16);
}

// ---------------- fp32 -> bf16 converts ----------------
__global__ void cvt_kernel(const float* __restrict__ src, u16* __restrict__ dst, int n) {
    int i = (blockIdx.x * blockDim.x + threadIdx.x) * 4;
    if (i >= n) return;
    float4 f = *(const float4*)(src + i);
    u16 o0 = f2bf(f.x), o1 = f2bf(f.y), o2 = f2bf(f.z), o3 = f2bf(f.w);
    dst[i+0] = o0; dst[i+1] = o1; dst[i+2] = o2; dst[i+3] = o3;
}

__global__ void cvt_w_kernel(const float* __restrict__ s0, const float* __restrict__ s1,
                             const float* __restrict__ s2, const float* __restrict__ s3,
                             u16* __restrict__ d0, u16* __restrict__ d1,
                             u16* __restrict__ d2, u16* __restrict__ d3) {
    const int wsel = blockIdx.y;
    const float* src = (wsel == 0) ? s0 : (wsel == 1) ? s1 : (wsel == 2) ? s2 : s3;
    u16*       dst  = (wsel == 0) ? d0 : (wsel == 1) ? d1 : (wsel == 2) ? d2 : d3;
    int i = (blockIdx.x * blockDim.x + threadIdx.x) * 4;
    float4 f = *(const float4*)(src + i);
    u16 o0 = f2bf(f.x), o1 = f2bf(f.y), o2 = f2bf(f.z), o3 = f2bf(f.w);
    dst[i+0] = o0; dst[i+1] = o1; dst[i+2] = o2; dst[i+3] = o3;
}

// ================= fused QKV GEMM, BK=64 =================
// grid (64, 24): by>>3 selects {Q,K,V}; n0=(by&7)*128.
// 128x128 tile, K-step 64: 32 MFMA per barrier pair (2x m97 density).
// LDS rows are 128B (8 chunks); xor-swizzle: row r chunk j stored at pos j^(r&7).
__global__ __launch_bounds__(256)
void gemm_qkv(const u16* __restrict__ A,
              const u16* __restrict__ Wq, const u16* __restrict__ Wk, const u16* __restrict__ Wv,
              const float* __restrict__ bq, const float* __restrict__ bk, const float* __restrict__ bv,
              u16* __restrict__ oq, u16* __restrict__ ok, u16* __restrict__ ov,
              float qscale)
{
    __shared__ u16 As[128*64];   // 16 KB
    __shared__ u16 Bs[128*64];   // 16 KB
    const int tid  = threadIdx.x;
    const int lane = tid & 63;
    const int wid  = tid >> 6;
    const int wm = wid >> 1, wn = wid & 1;
    const int quad = lane >> 4;
    const int l16  = lane & 15;
    const int bm0 = blockIdx.x * 128;
    const int sel = blockIdx.y >> 3;          // 0=Q 1=K 2=V
    const int bn0 = (blockIdx.y & 7) * 128;

    const u16*  Bw   = (sel == 0) ? Wq : (sel == 1) ? Wk : Wv;
    const float* bias = (sel == 0) ? bq : (sel == 1) ? bk : bv;
    u16*        out  = (sel == 0) ? oq : (sel == 1) ? ok : ov;
    const float scale = (sel == 0) ? qscale : 1.0f;

    floatx4 acc[4][4] = {};

    // staging: 1024 chunks/matrix; thread t covers chunks t,+256,+512,+768
    // chunk c: row=c>>3 (rows r0,+32,+64,+96: row&7 invariant), pos=c&7, global j=pos^(row&7)
    const int r0   = tid >> 3;
    const int joff = ((tid & 7) ^ ((tid >> 3) & 7)) * 8;   // shorts
    const u16* Ag0 = A  + (size_t)(bm0 + r0      ) * EMBED + joff;
    const u16* Ag1 = A  + (size_t)(bm0 + r0 + 32 ) * EMBED + joff;
    const u16* Ag2 = A  + (size_t)(bm0 + r0 + 64 ) * EMBED + joff;
    const u16* Ag3 = A  + (size_t)(bm0 + r0 + 96 ) * EMBED + joff;
    const u16* Bg0 = Bw + (size_t)(bn0 + r0      ) * EMBED + joff;
    const u16* Bg1 = Bw + (size_t)(bn0 + r0 + 32 ) * EMBED + joff;
    const u16* Bg2 = Bw + (size_t)(bn0 + r0 + 64 ) * EMBED + joff;
    const u16* Bg3 = Bw + (size_t)(bn0 + r0 + 96 ) * EMBED + joff;
    char* AsB = (char*)As;
    char* BsB = (char*)Bs;
    const int wbyte = wid * 1024;

    // fragment read: k-half 0 -> chunk quad, k-half 1 -> chunk quad+4 (xor 4)
    const int fpos0 = (quad ^ (l16 & 7)) * 8;   // shorts within 64-short row
    const int fpos1 = fpos0 ^ 32;

    for (int kk = 0; kk < EMBED; kk += 64) {
        __syncthreads();
        async16(Ag0 + kk, AsB + wbyte);
        async16(Ag1 + kk, AsB + wbyte + 4096);
        async16(Ag2 + kk, AsB + wbyte + 8192);
        async16(Ag3 + kk, AsB + wbyte + 12288);
        async16(Bg0 + kk, BsB + wbyte);
        async16(Bg1 + kk, BsB + wbyte + 4096);
        async16(Bg2 + kk, BsB + wbyte + 8192);
        async16(Bg3 + kk, BsB + wbyte + 12288);
        __syncthreads();

#pragma unroll
        for (int ks = 0; ks < 2; ks++) {
            const int fp = ks ? fpos1 : fpos0;
            short8 a[4], b[4];
#pragma unroll
            for (int i = 0; i < 4; i++)
                a[i] = *(const short8*)(As + (wm*64 + i*16 + l16)*64 + fp);
#pragma unroll
            for (int i = 0; i < 4; i++)
                b[i] = *(const short8*)(Bs + (wn*64 + i*16 + l16)*64 + fp);
#pragma unroll
            for (int i = 0; i < 4; i++)
#pragma unroll
                for (int j = 0; j < 4; j++)
                    acc[i][j] = __builtin_amdgcn_mfma_f32_16x16x32_bf16(a[i], b[j], acc[i][j], 0, 0, 0);
        }
    }

#pragma unroll
    for (int i = 0; i < 4; i++) {
#pragma unroll
        for (int j = 0; j < 4; j++) {
            const int col = bn0 + wn*64 + j*16 + l16;
            const float bvv = bias[col];
#pragma unroll
            for (int r = 0; r < 4; r++) {
                const int row = bm0 + wm*64 + i*16 + quad*4 + r;
                const float v = (acc[i][j][r] + bvv) * scale;
                const int bb = row >> 11, t = row & 2047;
                const int hh = col >> 6,  d = col & 63;
                if (sel != 2)
                    out[((size_t)(bb*HEADS + hh)*CTX + t)*HD + d] = f2bf(v);
                else
                    out[((size_t)(bb*HEADS + hh)*HD + d)*CTX + t] = f2bf(v);
            }
        }
    }
}

// ================= projection GEMM (fp32 out), BK=64 =================
__global__ __launch_bounds__(256)
void gemm_proj(const u16* __restrict__ A, const u16* __restrict__ Bw,
               const float* __restrict__ bias, float* __restrict__ out)
{
    __shared__ u16 As[128*64];
    __shared__ u16 Bs[128*64];
    const int tid  = threadIdx.x;
    const int lane = tid & 63;
    const int wid  = tid >> 6;
    const int wm = wid >> 1, wn = wid & 1;
    const int quad = lane >> 4;
    const int l16  = lane & 15;
    const int bm0 = blockIdx.x * 128;
    const int bn0 = blockIdx.y * 128;

    floatx4 acc[4][4] = {};

    const int r0   = tid >> 3;
    const int joff = ((tid & 7) ^ ((tid >> 3) & 7)) * 8;
    const u16* Ag0 = A  + (size_t)(bm0 + r0      ) * EMBED + joff;
    const u16* Ag1 = A  + (size_t)(bm0 + r0 + 32 ) * EMBED + joff;
    const u16* Ag2 = A  + (size_t)(bm0 + r0 + 64 ) * EMBED + joff;
    const u16* Ag3 = A  + (size_t)(bm0 + r0 + 96 ) * EMBED + joff;
    const u16* Bg0 = Bw + (size_t)(bn0 + r0      ) * EMBED + joff;
    const u16* Bg1 = Bw + (size_t)(bn0 + r0 + 32 ) * EMBED + joff;
    const u16* Bg2 = Bw + (size_t)(bn0 + r0 + 64 ) * EMBED + joff;
    const u16* Bg3 = Bw + (size_t)(bn0 + r0 + 96 ) * EMBED + joff;
    char* AsB = (char*)As;
    char* BsB = (char*)Bs;
    const int wbyte = wid * 1024;
    const int fpos0 = (quad ^ (l16 & 7)) * 8;
    const int fpos1 = fpos0 ^ 32;

    for (int kk = 0; kk < EMBED; kk += 64) {
        __syncthreads();
        async16(Ag0 + kk, AsB + wbyte);
        async16(Ag1 + kk, AsB + wbyte + 4096);
        async16(Ag2 + kk, AsB + wbyte + 8192);
        async16(Ag3 + kk, AsB + wbyte + 12288);
        async16(Bg0 + kk, BsB + wbyte);
        async16(Bg1 + kk, BsB + wbyte + 4096);
        async16(Bg2 + kk, BsB + wbyte + 8192);
        async16(Bg3 + kk, BsB + wbyte + 12288);
        __syncthreads();

#pragma unroll
        for (int ks = 0; ks < 2; ks++) {
            const int fp = ks ? fpos1 : fpos0;
            short8 a[4], b[4];
#pragma unroll
            for (int i = 0; i < 4; i++)
                a[i] = *(const short8*)(As + (wm*64 + i*16 + l16)*64 + fp);
#pragma unroll
            for (int i = 0; i < 4; i++)
                b[i] = *(const short8*)(Bs + (wn*64 + i*16 + l16)*64 + fp);
#pragma unroll
            for (int i = 0; i < 4; i++)
#pragma unroll
                for (int j = 0; j < 4; j++)
                    acc[i][j] = __builtin_amdgcn_mfma_f32_16x16x32_bf16(a[i], b[j], acc[i][j], 0, 0, 0);
        }
    }

#pragma unroll
    for (int i = 0; i < 4; i++) {
#pragma unroll
        for (int j = 0; j < 4; j++) {
            const int col = bn0 + wn*64 + j*16 + l16;
            const float bvv = bias[col];
#pragma unroll
            for (int r = 0; r < 4; r++) {
                const int row = bm0 + wm*64 + i*16 + quad*4 + r;
                out[(size_t)row * EMBED + col] = acc[i][j][r] + bvv;
            }
        }
    }
}

// ---------------- flash attention (causal, pair-balanced, XCD-grouped, dbuf) ----------------
// Double-buffered K/V: prefetch tile kt+1 (or pair-partner tile 0) right after the
// barrier, so async16s are in flight during the whole compute of tile kt; the
// compiler's vmcnt(0)-before-barrier then drains an already-complete queue.
// One barrier per tile. LDS 41.2 KB -> 3 blocks/CU (12 waves, same as measured).
#define PROW 72
__global__ __launch_bounds__(256)
void attn_kernel(const u16* __restrict__ Q, const u16* __restrict__ K,
                 const u16* __restrict__ Vt, u16* __restrict__ O)
{
    __shared__ u16 Ks[2][64*64];
    __shared__ u16 Vs[2][64*64];     // Vs[d][ki]
    __shared__ u16 Ps[4*16*PROW];    // per-wave P tile (padded)

    const int tid  = threadIdx.x, lane = tid & 63, w = tid >> 6;
    const int quad = lane >> 4, l16 = lane & 15;

    const int lid  = blockIdx.x;
    const int xcd  = lid & 7;
    const int slot = lid >> 3;           // 0..127
    const int bh   = xcd * 8 + (slot >> 4);
    const int bx   = slot & 15;
    const int h    = bh & (HEADS - 1);
    const int b    = bh >> 4;

    const u16* Qh = Q  + (size_t)bh * CTX * HD;
    const u16* Kh = K  + (size_t)bh * CTX * HD;
    const u16* Vh = Vt + (size_t)bh * HD * CTX;

    const int srow = tid >> 3;
    const int spos = tid & 7;
    const int joff = (spos ^ (srow & 7)) * 8;
    const int wbyte = w * 1024;
    u16* Pw = Ps + w * 16 * PROW;

    const int fpos0 = (quad ^ (l16 & 7)) * 8;
    const int fpos1 = fpos0 ^ 32;

    const int NQT = CTX / 64;  // 32
    const int qbA = bx, qbB = NQT - 1 - bx;

    auto stage = [&](int kt, int buf) {
        char* kb = (char*)(&Ks[buf][0]) + wbyte;
        char* vb = (char*)(&Vs[buf][0]) + wbyte;
        async16(Kh + (size_t)(kt*64 + srow     )*HD + joff, kb);
        async16(Kh + (size_t)(kt*64 + srow + 32)*HD + joff, kb + 4096);
        async16(Vh + (size_t)(srow     )*CTX + kt*64 + joff, vb);
        async16(Vh + (size_t)(srow + 32)*CTX + kt*64 + joff, vb + 4096);
    };

    int par = 0;
    stage(0, 0);   // pass-0 tile 0

#pragma unroll 1
    for (int pass = 0; pass < 2; pass++) {
        const int qb  = (pass == 0) ? qbA : qbB;
        const int qb0 = qb * 64;

        short8 qf[2];
        {
            const int row = qb0 + w*16 + l16;
#pragma unroll
            for (int ks = 0; ks < 2; ks++)
                qf[ks] = *(const short8*)(Qh + (size_t)row*HD + ks*32 + quad*8);
        }

        float lsum[4] = {0.f, 0.f, 0.f, 0.f};
        floatx4 o_acc[4] = {};

        for (int kt = 0; kt <= qb; kt++) {
            __syncthreads();   // drains stage(kt) (in flight since previous compute)

            // prefetch next tile into the other buffer
            if (kt < qb)            stage(kt + 1, par ^ 1);
            else if (pass == 0)     stage(0,      par ^ 1);   // pair partner's tile 0

            const u16* Kc = &Ks[par][0];
            const u16* Vc = &Vs[par][0];

            floatx4 s[4] = {};
#pragma unroll
            for (int ni = 0; ni < 4; ni++) {
                short8 kf0 = *(const short8*)(Kc + (ni*16 + l16)*64 + fpos0);
                short8 kf1 = *(const short8*)(Kc + (ni*16 + l16)*64 + fpos1);
                s[ni] = __builtin_amdgcn_mfma_f32_16x16x32_bf16(qf[0], kf0, s[ni], 0, 0, 0);
                s[ni] = __builtin_amdgcn_mfma_f32_16x16x32_bf16(qf[1], kf1, s[ni], 0, 0, 0);
            }

            const bool diag = (kt == qb);
#pragma unroll
            for (int ni = 0; ni < 4; ni++) {
#pragma unroll
                for (int r = 0; r < 4; r++) {
                    float v = s[ni][r];
                    if (diag) {
                        const int qrow = qb0 + w*16 + quad*4 + r;
                        const int key  = kt*64 + ni*16 + l16;
                        if (key > qrow) v = -INFINITY;
                    }
                    const float p = __builtin_amdgcn_exp2f(v);
                    lsum[r] += p;
                    Pw[(quad*4 + r)*PROW + ni*16 + l16] = f2bf_rtz(p);
                }
            }

            short8 pf0 = *(const short8*)(Pw + l16*PROW + quad*8);
            short8 pf1 = *(const short8*)(Pw + l16*PROW + 32 + quad*8);
#pragma unroll
            for (int ni = 0; ni < 4; ni++) {
                short8 vf0 = *(const short8*)(Vc + (ni*16 + l16)*64 + fpos0);
                short8 vf1 = *(const short8*)(Vc + (ni*16 + l16)*64 + fpos1);
                o_acc[ni] = __builtin_amdgcn_mfma_f32_16x16x32_bf16(pf0, vf0, o_acc[ni], 0, 0, 0);
                o_acc[ni] = __builtin_amdgcn_mfma_f32_16x16x32_bf16(pf1, vf1, o_acc[ni], 0, 0, 0);
            }

            par ^= 1;
        }

        float linv[4];
#pragma unroll
        for (int r = 0; r < 4; r++) {
#pragma unroll
            for (int off = 1; off < 16; off <<= 1)
                lsum[r] += __shfl_xor(lsum[r], off);
            linv[r] = 1.f / lsum[r];
        }

        u16* Ob = O + ((size_t)b * CTX) * EMBED + (size_t)h * HD;
#pragma unroll
        for (int ni = 0; ni < 4; ni++)
#pragma unroll
            for (int r = 0; r < 4; r++) {
                const int qrow = qb0 + w*16 + quad*4 + r;
                const int d = ni*16 + l16;
                Ob[(size_t)qrow * EMBED + d] = f2bf(o_acc[ni][r] * linv[r]);
            }
    }
}

// ---------------- launcher ----------------
extern "C" void kernel_launch(void* const* d_in, const int* in_sizes, int n_in,
                              void* d_out, int out_size, void* d_ws, size_t ws_size,
                              hipStream_t stream) {
    const float* x  = (const float*)d_in[0];
    const float* Wq = (const float*)d_in[1];
    const float* bq = (const float*)d_in[2];
    const float* Wk = (const float*)d_in[3];
    const float* bk = (const float*)d_in[4];
    const float* Wv = (const float*)d_in[5];
    const float* bv = (const float*)d_in[6];
    const float* Wp = (const float*)d_in[7];
    const float* bp = (const float*)d_in[8];

    char* ws = (char*)d_ws;
    const size_t XSZ = (size_t)M_TOT * EMBED * 2;   // 16 MB
    const size_t WSZ = (size_t)EMBED * EMBED * 2;   // 2 MB
    u16* xb  = (u16*)ws;                 ws += XSZ;
    u16* wqb = (u16*)ws;                 ws += WSZ;
    u16* wkb = (u16*)ws;                 ws += WSZ;
    u16* wvb = (u16*)ws;                 ws += WSZ;
    u16* wpb = (u16*)ws;                 ws += WSZ;
    u16* qg  = (u16*)ws;                 ws += XSZ;
    u16* kg  = (u16*)ws;                 ws += XSZ;
    u16* vtg = (u16*)ws;                 ws += XSZ;
    u16* og  = xb;   // x-bf16 dead after QKV GEMM; attn output reuses it

    const int nX = M_TOT * EMBED;
    const int nW = EMBED * EMBED;
    cvt_kernel<<<nX/1024, 256, 0, stream>>>(x, xb, nX);
    cvt_w_kernel<<<dim3(nW/1024, 4), 256, 0, stream>>>(Wq, Wk, Wv, Wp, wqb, wkb, wvb, wpb);

    const float qscale = 0.125f * 1.44269504f;  // 1/sqrt(64) * log2(e)
    gemm_qkv<<<dim3(M_TOT/128, 24), 256, 0, stream>>>(xb, wqb, wkb, wvb, bq, bk, bv,
                                                      qg, kg, vtg, qscale);

    attn_kernel<<<dim3(1024), 256, 0, stream>>>(qg, kg, vtg, og);

    gemm_proj<<<dim3(M_TOT/128, EMBED/128), 256, 0, stream>>>(og, wpb, bp, (float*)d_out);
}

// Round 6
// 264.791 us; speedup vs baseline: 1.0589x; 1.0589x over previous
//
#include <hip/hip_runtime.h>
#include <hip/hip_bf16.h>
#include <stdint.h>

#define EMBED 1024
#define HEADS 16
#define CTX   2048
#define BATCH 4
#define HD    64
#define M_TOT (BATCH*CTX)   // 8192

typedef unsigned short u16;
typedef __attribute__((ext_vector_type(8))) short short8;   // 8 bf16 (4 VGPRs)
typedef __attribute__((ext_vector_type(4))) float floatx4;  // MFMA C/D

typedef const __attribute__((address_space(1))) unsigned int g_u32;
typedef __attribute__((address_space(3))) unsigned int l_u32;

__device__ __forceinline__ void async16(const void* g, void* l) {
    __builtin_amdgcn_global_load_lds((g_u32*)g, (l_u32*)l, 16, 0, 0);
}

__device__ __forceinline__ u16 f2bf(float f) {          // round-nearest-even
    uint32_t u = __float_as_uint(f);
    uint32_t r = (u + 0x7FFFu + ((u >> 16) & 1u)) >> 16;
    return (u16)r;
}

// ---------------- fp32 -> bf16 converts ----------------
__global__ void cvt_kernel(const float* __restrict__ src, u16* __restrict__ dst, int n) {
    int i = (blockIdx.x * blockDim.x + threadIdx.x) * 4;
    if (i >= n) return;
    float4 f = *(const float4*)(src + i);
    u16 o0 = f2bf(f.x), o1 = f2bf(f.y), o2 = f2bf(f.z), o3 = f2bf(f.w);
    dst[i+0] = o0; dst[i+1] = o1; dst[i+2] = o2; dst[i+3] = o3;
}

__global__ void cvt_w_kernel(const float* __restrict__ s0, const float* __restrict__ s1,
                             const float* __restrict__ s2, const float* __restrict__ s3,
                             u16* __restrict__ d0, u16* __restrict__ d1,
                             u16* __restrict__ d2, u16* __restrict__ d3) {
    const int wsel = blockIdx.y;
    const float* src = (wsel == 0) ? s0 : (wsel == 1) ? s1 : (wsel == 2) ? s2 : s3;
    u16*       dst  = (wsel == 0) ? d0 : (wsel == 1) ? d1 : (wsel == 2) ? d2 : d3;
    int i = (blockIdx.x * blockDim.x + threadIdx.x) * 4;
    float4 f = *(const float4*)(src + i);
    u16 o0 = f2bf(f.x), o1 = f2bf(f.y), o2 = f2bf(f.z), o3 = f2bf(f.w);
    dst[i+0] = o0; dst[i+1] = o1; dst[i+2] = o2; dst[i+3] = o3;
}

// ================= fused QKV GEMM, BK=64 =================
__global__ __launch_bounds__(256)
void gemm_qkv(const u16* __restrict__ A,
              const u16* __restrict__ Wq, const u16* __restrict__ Wk, const u16* __restrict__ Wv,
              const float* __restrict__ bq, const float* __restrict__ bk, const float* __restrict__ bv,
              u16* __restrict__ oq, u16* __restrict__ ok, u16* __restrict__ ov,
              float qscale)
{
    __shared__ u16 As[128*64];   // 16 KB
    __shared__ u16 Bs[128*64];   // 16 KB
    const int tid  = threadIdx.x;
    const int lane = tid & 63;
    const int wid  = tid >> 6;
    const int wm = wid >> 1, wn = wid & 1;
    const int quad = lane >> 4;
    const int l16  = lane & 15;
    const int bm0 = blockIdx.x * 128;
    const int sel = blockIdx.y >> 3;          // 0=Q 1=K 2=V
    const int bn0 = (blockIdx.y & 7) * 128;

    const u16*  Bw   = (sel == 0) ? Wq : (sel == 1) ? Wk : Wv;
    const float* bias = (sel == 0) ? bq : (sel == 1) ? bk : bv;
    u16*        out  = (sel == 0) ? oq : (sel == 1) ? ok : ov;
    const float scale = (sel == 0) ? qscale : 1.0f;

    floatx4 acc[4][4] = {};

    const int r0   = tid >> 3;
    const int joff = ((tid & 7) ^ ((tid >> 3) & 7)) * 8;   // shorts
    const u16* Ag0 = A  + (size_t)(bm0 + r0      ) * EMBED + joff;
    const u16* Ag1 = A  + (size_t)(bm0 + r0 + 32 ) * EMBED + joff;
    const u16* Ag2 = A  + (size_t)(bm0 + r0 + 64 ) * EMBED + joff;
    const u16* Ag3 = A  + (size_t)(bm0 + r0 + 96 ) * EMBED + joff;
    const u16* Bg0 = Bw + (size_t)(bn0 + r0      ) * EMBED + joff;
    const u16* Bg1 = Bw + (size_t)(bn0 + r0 + 32 ) * EMBED + joff;
    const u16* Bg2 = Bw + (size_t)(bn0 + r0 + 64 ) * EMBED + joff;
    const u16* Bg3 = Bw + (size_t)(bn0 + r0 + 96 ) * EMBED + joff;
    char* AsB = (char*)As;
    char* BsB = (char*)Bs;
    const int wbyte = wid * 1024;

    const int fpos0 = (quad ^ (l16 & 7)) * 8;
    const int fpos1 = fpos0 ^ 32;

    for (int kk = 0; kk < EMBED; kk += 64) {
        __syncthreads();
        async16(Ag0 + kk, AsB + wbyte);
        async16(Ag1 + kk, AsB + wbyte + 4096);
        async16(Ag2 + kk, AsB + wbyte + 8192);
        async16(Ag3 + kk, AsB + wbyte + 12288);
        async16(Bg0 + kk, BsB + wbyte);
        async16(Bg1 + kk, BsB + wbyte + 4096);
        async16(Bg2 + kk, BsB + wbyte + 8192);
        async16(Bg3 + kk, BsB + wbyte + 12288);
        __syncthreads();

#pragma unroll
        for (int ks = 0; ks < 2; ks++) {
            const int fp = ks ? fpos1 : fpos0;
            short8 a[4], b[4];
#pragma unroll
            for (int i = 0; i < 4; i++)
                a[i] = *(const short8*)(As + (wm*64 + i*16 + l16)*64 + fp);
#pragma unroll
            for (int i = 0; i < 4; i++)
                b[i] = *(const short8*)(Bs + (wn*64 + i*16 + l16)*64 + fp);
#pragma unroll
            for (int i = 0; i < 4; i++)
#pragma unroll
                for (int j = 0; j < 4; j++)
                    acc[i][j] = __builtin_amdgcn_mfma_f32_16x16x32_bf16(a[i], b[j], acc[i][j], 0, 0, 0);
        }
    }

#pragma unroll
    for (int i = 0; i < 4; i++) {
#pragma unroll
        for (int j = 0; j < 4; j++) {
            const int col = bn0 + wn*64 + j*16 + l16;
            const float bvv = bias[col];
#pragma unroll
            for (int r = 0; r < 4; r++) {
                const int row = bm0 + wm*64 + i*16 + quad*4 + r;
                const float v = (acc[i][j][r] + bvv) * scale;
                const int bb = row >> 11, t = row & 2047;
                const int hh = col >> 6,  d = col & 63;
                if (sel != 2)
                    out[((size_t)(bb*HEADS + hh)*CTX + t)*HD + d] = f2bf(v);
                else
                    out[((size_t)(bb*HEADS + hh)*HD + d)*CTX + t] = f2bf(v);
            }
        }
    }
}

// ================= projection GEMM (fp32 out), BK=64 =================
__global__ __launch_bounds__(256)
void gemm_proj(const u16* __restrict__ A, const u16* __restrict__ Bw,
               const float* __restrict__ bias, float* __restrict__ out)
{
    __shared__ u16 As[128*64];
    __shared__ u16 Bs[128*64];
    const int tid  = threadIdx.x;
    const int lane = tid & 63;
    const int wid  = tid >> 6;
    const int wm = wid >> 1, wn = wid & 1;
    const int quad = lane >> 4;
    const int l16  = lane & 15;
    const int bm0 = blockIdx.x * 128;
    const int bn0 = blockIdx.y * 128;

    floatx4 acc[4][4] = {};

    const int r0   = tid >> 3;
    const int joff = ((tid & 7) ^ ((tid >> 3) & 7)) * 8;
    const u16* Ag0 = A  + (size_t)(bm0 + r0      ) * EMBED + joff;
    const u16* Ag1 = A  + (size_t)(bm0 + r0 + 32 ) * EMBED + joff;
    const u16* Ag2 = A  + (size_t)(bm0 + r0 + 64 ) * EMBED + joff;
    const u16* Ag3 = A  + (size_t)(bm0 + r0 + 96 ) * EMBED + joff;
    const u16* Bg0 = Bw + (size_t)(bn0 + r0      ) * EMBED + joff;
    const u16* Bg1 = Bw + (size_t)(bn0 + r0 + 32 ) * EMBED + joff;
    const u16* Bg2 = Bw + (size_t)(bn0 + r0 + 64 ) * EMBED + joff;
    const u16* Bg3 = Bw + (size_t)(bn0 + r0 + 96 ) * EMBED + joff;
    char* AsB = (char*)As;
    char* BsB = (char*)Bs;
    const int wbyte = wid * 1024;
    const int fpos0 = (quad ^ (l16 & 7)) * 8;
    const int fpos1 = fpos0 ^ 32;

    for (int kk = 0; kk < EMBED; kk += 64) {
        __syncthreads();
        async16(Ag0 + kk, AsB + wbyte);
        async16(Ag1 + kk, AsB + wbyte + 4096);
        async16(Ag2 + kk, AsB + wbyte + 8192);
        async16(Ag3 + kk, AsB + wbyte + 12288);
        async16(Bg0 + kk, BsB + wbyte);
        async16(Bg1 + kk, BsB + wbyte + 4096);
        async16(Bg2 + kk, BsB + wbyte + 8192);
        async16(Bg3 + kk, BsB + wbyte + 12288);
        __syncthreads();

#pragma unroll
        for (int ks = 0; ks < 2; ks++) {
            const int fp = ks ? fpos1 : fpos0;
            short8 a[4], b[4];
#pragma unroll
            for (int i = 0; i < 4; i++)
                a[i] = *(const short8*)(As + (wm*64 + i*16 + l16)*64 + fp);
#pragma unroll
            for (int i = 0; i < 4; i++)
                b[i] = *(const short8*)(Bs + (wn*64 + i*16 + l16)*64 + fp);
#pragma unroll
            for (int i = 0; i < 4; i++)
#pragma unroll
                for (int j = 0; j < 4; j++)
                    acc[i][j] = __builtin_amdgcn_mfma_f32_16x16x32_bf16(a[i], b[j], acc[i][j], 0, 0, 0);
        }
    }

#pragma unroll
    for (int i = 0; i < 4; i++) {
#pragma unroll
        for (int j = 0; j < 4; j++) {
            const int col = bn0 + wn*64 + j*16 + l16;
            const float bvv = bias[col];
#pragma unroll
            for (int r = 0; r < 4; r++) {
                const int row = bm0 + wm*64 + i*16 + quad*4 + r;
                out[(size_t)row * EMBED + col] = acc[i][j][r] + bvv;
            }
        }
    }
}

// ---------------- flash attention v3: 128 q/block, S^T order, swizzled P ----------------
// Grid 512 (XCD-grouped): xcd=lid&7 -> 8 bh each; bx in 0..7 pairs q-tiles (bx, 15-bx)
// of 128 rows -> constant 34 key-tiles/block.
// Wave owns 32 q rows (2 subtiles of 16). S computed TRANSPOSED (A=K, B=Q) so the
// C-layout holds P with q=col: each lane owns 4 consecutive ki for fixed q ->
// P stores are packed ds_write_b64; P re-read (A-operand for PV) is ds_read_b128.
// P buffer row=128B, chunk xor-swizzled by (row&7) -> <=2-way banks everywhere.
__global__ __launch_bounds__(256)
void attn_kernel(const u16* __restrict__ Q, const u16* __restrict__ K,
                 const u16* __restrict__ Vt, u16* __restrict__ O)
{
    __shared__ u16 Ks[2][64*64];     // 2 x 8 KB
    __shared__ u16 Vs[2][64*64];     // 2 x 8 KB   Vs[d][ki]
    __shared__ u16 Ps[4*32*64];      // 16 KB, per-wave 32 rows x 64 ki

    const int tid  = threadIdx.x, lane = tid & 63, w = tid >> 6;
    const int quad = lane >> 4, l16 = lane & 15;

    const int lid  = blockIdx.x;            // 0..511
    const int xcd  = lid & 7;
    const int slot = lid >> 3;              // 0..63
    const int bh   = xcd * 8 + (slot >> 3);
    const int bx   = slot & 7;              // 0..7
    const int h    = bh & (HEADS - 1);
    const int b    = bh >> 4;

    const u16* Qh = Q  + (size_t)bh * CTX * HD;
    const u16* Kh = K  + (size_t)bh * CTX * HD;
    const u16* Vh = Vt + (size_t)bh * HD * CTX;

    const int srow = tid >> 3;
    const int joff = ((tid & 7) ^ (srow & 7)) * 8;
    const int wbyte = w * 1024;
    char* PwB = (char*)(Ps + w * 32 * 64);
    const int sw = l16 & 7;                 // swizzle key (row&7 for all our rows)

    auto stage = [&](int kt, int buf) {
        char* kb = (char*)(&Ks[buf][0]) + wbyte;
        char* vb = (char*)(&Vs[buf][0]) + wbyte;
        async16(Kh + (size_t)(kt*64 + srow     )*HD + joff, kb);
        async16(Kh + (size_t)(kt*64 + srow + 32)*HD + joff, kb + 4096);
        async16(Vh + (size_t)(srow     )*CTX + kt*64 + joff, vb);
        async16(Vh + (size_t)(srow + 32)*CTX + kt*64 + joff, vb + 4096);
    };

    int par = 0;
    stage(0, 0);

#pragma unroll 1
    for (int pass = 0; pass < 2; pass++) {
        const int qb  = (pass == 0) ? bx : (15 - bx);
        const int qb0 = qb * 128;
        const int KT  = 2*qb + 2;

        // Q fragments (B-operand: n=q=l16, k=d): qf[subtile][kstep]
        short8 qf[2][2];
#pragma unroll
        for (int st = 0; st < 2; st++)
#pragma unroll
            for (int ks = 0; ks < 2; ks++)
                qf[st][ks] = *(const short8*)(Qh + (size_t)(qb0 + w*32 + st*16 + l16)*HD
                                              + ks*32 + quad*8);

        float lsum[2] = {0.f, 0.f};
        floatx4 o_acc[2][4] = {};

        for (int kt = 0; kt < KT; kt++) {
            __syncthreads();   // drains stage(kt), in flight since previous compute

            if (kt + 1 < KT)      stage(kt + 1, par ^ 1);
            else if (pass == 0)   stage(0,      par ^ 1);

            const char* KcB = (const char*)(&Ks[par][0]);
            const char* VcB = (const char*)(&Vs[par][0]);

            // S^T = K Q^T : m=ki (row=quad*4+r), n=q (col=l16)
            floatx4 s[2][4] = {};
#pragma unroll
            for (int ks = 0; ks < 2; ks++) {
#pragma unroll
                for (int ni = 0; ni < 4; ni++) {
                    short8 kf = *(const short8*)(KcB + (ni*16 + l16)*128
                                                 + (((4*ks + quad) ^ sw) * 16));
                    s[0][ni] = __builtin_amdgcn_mfma_f32_16x16x32_bf16(kf, qf[0][ks], s[0][ni], 0, 0, 0);
                    s[1][ni] = __builtin_amdgcn_mfma_f32_16x16x32_bf16(kf, qf[1][ks], s[1][ni], 0, 0, 0);
                }
            }

            // P = exp2(S'), mask on last two tiles, packed b64 stores to swizzled P
            const bool mt = (kt >= 2*qb);
            const int key0 = kt * 64;
#pragma unroll
            for (int st = 0; st < 2; st++) {
                const int qrow = qb0 + w*32 + st*16 + l16;
#pragma unroll
                for (int ni = 0; ni < 4; ni++) {
                    float p[4];
#pragma unroll
                    for (int r = 0; r < 4; r++) {
                        float v = s[st][ni][r];
                        if (mt) {
                            const int key = key0 + ni*16 + quad*4 + r;
                            if (key > qrow) v = -INFINITY;
                        }
                        p[r] = __builtin_amdgcn_exp2f(v);
                        lsum[st] += p[r];
                    }
                    uint2 pk;
                    pk.x = (__float_as_uint(p[0]) >> 16) | (__float_as_uint(p[1]) & 0xFFFF0000u);
                    pk.y = (__float_as_uint(p[2]) >> 16) | (__float_as_uint(p[3]) & 0xFFFF0000u);
                    *(uint2*)(PwB + (st*16 + l16)*128
                              + (((2*ni + (quad >> 1)) ^ sw) * 16) + (quad & 1) * 8) = pk;
                }
            }

            // O += P V : A=P (m=q), B=Vt rows (n=d, k=ki)
#pragma unroll
            for (int ks = 0; ks < 2; ks++) {
                const int pco = ((4*ks + quad) ^ sw) * 16;
                short8 pf0 = *(const short8*)(PwB + (l16     )*128 + pco);
                short8 pf1 = *(const short8*)(PwB + (16 + l16)*128 + pco);
#pragma unroll
                for (int ni = 0; ni < 4; ni++) {
                    short8 vf = *(const short8*)(VcB + (ni*16 + l16)*128 + pco);
                    o_acc[0][ni] = __builtin_amdgcn_mfma_f32_16x16x32_bf16(pf0, vf, o_acc[0][ni], 0, 0, 0);
                    o_acc[1][ni] = __builtin_amdgcn_mfma_f32_16x16x32_bf16(pf1, vf, o_acc[1][ni], 0, 0, 0);
                }
            }

            par ^= 1;
        }

        // l-sum: reduce across the 4 quads (lane l has sum for q=l&15), then
        // redistribute reciprocal to the C-layout lanes (q = quad*4+r).
        float linv[2][4];
#pragma unroll
        for (int st = 0; st < 2; st++) {
            lsum[st] += __shfl_xor(lsum[st], 16);
            lsum[st] += __shfl_xor(lsum[st], 32);
            const float rinv = 1.f / lsum[st];
#pragma unroll
            for (int r = 0; r < 4; r++)
                linv[st][r] = __shfl(rinv, quad*4 + r);
        }

        u16* Ob = O + ((size_t)b * CTX) * EMBED + (size_t)h * HD;
#pragma unroll
        for (int st = 0; st < 2; st++)
#pragma unroll
            for (int ni = 0; ni < 4; ni++)
#pragma unroll
                for (int r = 0; r < 4; r++) {
                    const int qrow = qb0 + w*32 + st*16 + quad*4 + r;
                    Ob[(size_t)qrow * EMBED + ni*16 + l16] = f2bf(o_acc[st][ni][r] * linv[st][r]);
                }
    }
}

// ---------------- launcher ----------------
extern "C" void kernel_launch(void* const* d_in, const int* in_sizes, int n_in,
                              void* d_out, int out_size, void* d_ws, size_t ws_size,
                              hipStream_t stream) {
    const float* x  = (const float*)d_in[0];
    const float* Wq = (const float*)d_in[1];
    const float* bq = (const float*)d_in[2];
    const float* Wk = (const float*)d_in[3];
    const float* bk = (const float*)d_in[4];
    const float* Wv = (const float*)d_in[5];
    const float* bv = (const float*)d_in[6];
    const float* Wp = (const float*)d_in[7];
    const float* bp = (const float*)d_in[8];

    char* ws = (char*)d_ws;
    const size_t XSZ = (size_t)M_TOT * EMBED * 2;   // 16 MB
    const size_t WSZ = (size_t)EMBED * EMBED * 2;   // 2 MB
    u16* xb  = (u16*)ws;                 ws += XSZ;
    u16* wqb = (u16*)ws;                 ws += WSZ;
    u16* wkb = (u16*)ws;                 ws += WSZ;
    u16* wvb = (u16*)ws;                 ws += WSZ;
    u16* wpb = (u16*)ws;                 ws += WSZ;
    u16* qg  = (u16*)ws;                 ws += XSZ;
    u16* kg  = (u16*)ws;                 ws += XSZ;
    u16* vtg = (u16*)ws;                 ws += XSZ;
    u16* og  = xb;   // x-bf16 dead after QKV GEMM; attn output reuses it

    const int nX = M_TOT * EMBED;
    const int nW = EMBED * EMBED;
    cvt_kernel<<<nX/1024, 256, 0, stream>>>(x, xb, nX);
    cvt_w_kernel<<<dim3(nW/1024, 4), 256, 0, stream>>>(Wq, Wk, Wv, Wp, wqb, wkb, wvb, wpb);

    const float qscale = 0.125f * 1.44269504f;  // 1/sqrt(64) * log2(e)
    gemm_qkv<<<dim3(M_TOT/128, 24), 256, 0, stream>>>(xb, wqb, wkb, wvb, bq, bk, bv,
                                                      qg, kg, vtg, qscale);

    attn_kernel<<<dim3(512), 256, 0, stream>>>(qg, kg, vtg, og);

    gemm_proj<<<dim3(M_TOT/128, EMBED/128), 256, 0, stream>>>(og, wpb, bp, (float*)d_out);
}